// Round 1
// 174.818 us; speedup vs baseline: 1.0089x; 1.0089x over previous
//
#include <hip/hip_runtime.h>
#include <math.h>

// Problem constants
#define NB   4      // batch
#define CIN  64     // channels everywhere (I=CR=CA=CO=64)
#define HH   48
#define WW   48
#define HW   2304   // 48*48
#define DD   2116   // 46*46 (true d count; padded space is 2304)
#define NHEAD 4
#define HC   16
#define NT   144    // d-tiles in padded 48x48 d-space (2304 = 144*16; 188 zero-pads)
#define QTL  144    // q-tiles (2304 = 144*16)
#define PS   40000  // xb plane stride in shorts (2500 cells * 16)

typedef short  s4 __attribute__((ext_vector_type(4)));
typedef short  s8 __attribute__((ext_vector_type(8)));
typedef float  f4 __attribute__((ext_vector_type(4)));
typedef __bf16 b8 __attribute__((ext_vector_type(8)));

__device__ __forceinline__ f4 mm32(s8 a, s8 b, f4 c) {
    return __builtin_amdgcn_mfma_f32_16x16x32_bf16(
        __builtin_bit_cast(b8, a), __builtin_bit_cast(b8, b), c, 0, 0, 0);
}

__device__ __forceinline__ void split4(f4 a, s4& hi, s4& lo) {
    #pragma unroll
    for (int r = 0; r < 4; ++r) {
        unsigned u = __builtin_bit_cast(unsigned, a[r]);
        hi[r] = (short)(u >> 16);
        float l = a[r] - __builtin_bit_cast(float, u & 0xffff0000u);
        lo[r] = (short)(__builtin_bit_cast(unsigned, l) >> 16);
    }
}

// ---------------------------------------------------------------------------
// Fused input-projection + weight repack + a2m init + K/V pad-tile zeroing.
// NEW xb layout (for K=32 kq-pair fused MFMA): plane = n*8 + p*4 + q
// (p = kq-pair 0..1, q = lane-quad 0..3); per cell 16 shorts:
//   [hi(h=0,j0..3) | hi(h=1,j0..3) | lo(h=0,j0..3) | lo(h=1,j0..3)]
// covering channels c = 32p + 16h + 4q + j.
// Blocks 0..639: xb. 640..783: Wb. 784: a2m=0. 785..800: zero K/V tiles 138..143.
__global__ __launch_bounds__(256) void k_xw(const float* __restrict__ x,
                                            const float* __restrict__ Win,
                                            const float* __restrict__ bin,
                                            const float* __restrict__ Wq,
                                            const float* __restrict__ Wk,
                                            const float* __restrict__ Wv,
                                            unsigned short* __restrict__ xb,
                                            unsigned short* __restrict__ Wb,
                                            float* __restrict__ a2m,
                                            unsigned short* __restrict__ Kb,
                                            unsigned short* __restrict__ Vb) {
    int b = blockIdx.x;
    if (b == 784) {
        a2m[threadIdx.x] = 0.f;        // 256 = NB*CIN; k_conv cv==3 accumulates
        return;
    }
    if (b > 784) {
        // zero y-pad d-tiles (rows 46,47 -> tiles 138..143) of Kb and VbDup
        int nh = b - 785;
        s8 z = (s8){0, 0, 0, 0, 0, 0, 0, 0};
        for (int i = threadIdx.x; i < 1152; i += 256) {
            if (i < 384) *(s8*)(Kb + ((size_t)nh * NT + 138) * 512  + (size_t)i * 8) = z;
            else         *(s8*)(Vb + ((size_t)nh * NT + 138) * 1024 + (size_t)(i - 384) * 8) = z;
        }
        return;
    }
    if (b < 640) {
        int bx = b % 10, n = (b / 10) & 3, ocg = b / 40;
        int cell = bx * 256 + threadIdx.x;
        if (cell >= 2500) return;
        int cy = cell / 50, cx = cell - cy * 50;
        float a[4] = {0.f, 0.f, 0.f, 0.f};
        if (cy >= 1 && cy <= 48 && cx >= 1 && cx <= 48) {
            int px = (cy - 1) * 48 + (cx - 1);
            const float* xp = x + (size_t)(n * CIN) * HW + px;
            #pragma unroll
            for (int j = 0; j < 4; ++j) a[j] = bin[ocg * 4 + j];
            #pragma unroll 8
            for (int ic = 0; ic < CIN; ++ic) {
                float xv = xp[ic * HW];
                a[0] += Win[(ocg * 4 + 0) * CIN + ic] * xv;
                a[1] += Win[(ocg * 4 + 1) * CIN + ic] * xv;
                a[2] += Win[(ocg * 4 + 2) * CIN + ic] * xv;
                a[3] += Win[(ocg * 4 + 3) * CIN + ic] * xv;
            }
        }
        s4 hi, lo;
        #pragma unroll
        for (int j = 0; j < 4; ++j) {
            unsigned u = __builtin_bit_cast(unsigned, a[j]);
            hi[j] = (short)(u >> 16);
            float l = a[j] - __builtin_bit_cast(float, u & 0xffff0000u);
            lo[j] = (short)(__builtin_bit_cast(unsigned, l) >> 16);
        }
        int p = ocg >> 3, h = (ocg >> 2) & 1, q = ocg & 3;
        unsigned short* d = xb + ((size_t)(n * 8 + p * 4 + q) * 2500 + cell) * 16 + h * 4;
        *(s4*)(d)     = hi;
        *(s4*)(d + 8) = lo;
    } else {
        // Wb layout: per (cq,tap): [p=0: H 512 | L 512][p=1: H | L]; within plane
        // slot (m*4 + q)*8 + h*4 + j  -> channel k = 32p+16h+4q+j, oc row m.
        int bx = b - 640;
        int cq = bx / 9, tap = bx - cq * 9;
        int cv = cq >> 2, ocq = cq & 3;
        const float* src = (cv == 0) ? Wq : (cv == 1) ? Wk : (cv == 2) ? Wv
                                                          : (Wv + 2 * CIN * CIN * 9);
        int t = threadIdx.x;
        int m = t >> 4, kl = t & 15, q = kl >> 2, j = kl & 3;
        #pragma unroll
        for (int kq = 0; kq < 4; ++kq) {
            int p = kq >> 1, h = kq & 1;
            float v = src[((size_t)(ocq * 16 + m) * CIN + kq * 16 + kl) * 9 + tap];
            unsigned u = __builtin_bit_cast(unsigned, v);
            float lo = v - __builtin_bit_cast(float, u & 0xffff0000u);
            size_t base = ((size_t)(cq * 9 + tap) * 2 + p) * 1024 + (m * 4 + q) * 8 + h * 4 + j;
            Wb[base]       = (unsigned short)(u >> 16);
            Wb[base + 512] = (unsigned short)(__builtin_bit_cast(unsigned, lo) >> 16);
        }
    }
}

// ---------------------------------------------------------------------------
// Conv with K=32 fused MFMA (kq-pair packing): per tap, 18 mfma_16x16x32
// replace 36 mfma_16x16x16 at identical load count/bytes and identical
// numerics (hi*hi + lo*hi + hi*lo). Epilogues:
//  cv=0: Q tiles (unchanged layout).
//  cv=1: K tiles DIRECT (interleaved [khi4|klo4] per (dloc,cquad)) - k_cvt gone.
//  cv=2: V dup-tiles DIRECT via per-wave LDS transpose, coalesced 16B stores.
//  cv=3: v2 row-sums -> a2m (unchanged).
// d-space is 48x48-padded (NT=144): tile = y*3+xt, dloc = m16; x>=46 slots
// stored as zeros (=> exp(0)=1 per pad column; k_gates subtracts 188).
// grid (48 y, 4 n, 4 cv), block 256 = 4 waves = 4 oc-groups.
__global__ __launch_bounds__(256, 3) void k_conv(const unsigned short* __restrict__ xb,
                                                 const unsigned short* __restrict__ Wb,
                                                 unsigned short* __restrict__ Qb,
                                                 unsigned short* __restrict__ Kb,
                                                 unsigned short* __restrict__ Vb,
                                                 float* __restrict__ a2m) {
    __shared__ float sv[4][16][49];
    int y = blockIdx.x, n = blockIdx.y, cv = blockIdx.z;
    int outw = (cv == 0) ? 48 : 46;
    int pd   = (cv == 0) ? 0 : 1;
    if (y >= outw) return;
    int lane = threadIdx.x & 63, wv = threadIdx.x >> 6;
    int m16 = lane & 15, quad = lane >> 4;
    int cq = cv * 4 + wv;
    const unsigned short* Wt = Wb + (size_t)cq * 9 * 2048 + (m16 * 4 + quad) * 8;
    // OOB impossible: worst cell 49*50+2+15+32 = 2499 < 2500.
    const unsigned short* X0 = xb + ((size_t)(n * 8 + quad) * 2500
                                     + (size_t)(y + pd) * 50 + pd + m16) * 16;

    f4 a0 = {0.f, 0.f, 0.f, 0.f}, a1 = a0, a2c = a0;

    s8 w[4], xr[12];                       // w: p*2+{H,L}; xr: p*6+col*2+{H,L}
    #pragma unroll
    for (int p = 0; p < 2; ++p) {          // tap 0 prefetch
        w[p * 2]     = *(const s8*)(Wt + p * 1024);
        w[p * 2 + 1] = *(const s8*)(Wt + p * 1024 + 512);
        #pragma unroll
        for (int col = 0; col < 3; ++col) {
            const unsigned short* bq = X0 + (size_t)p * 160000 + col * 256;
            xr[p * 6 + col * 2]     = *(const s8*)(bq);
            xr[p * 6 + col * 2 + 1] = *(const s8*)(bq + 8);
        }
    }
    __builtin_amdgcn_sched_group_barrier(0x020, 16, 0);

    #pragma unroll
    for (int tap = 0; tap < 9; ++tap) {
        s8 wn[4], xn[12];
        if (tap < 8) {
            int tn = tap + 1;
            int dy = tn / 3, dx = tn - dy * 3;
            const unsigned short* wp  = Wt + tn * 2048;
            const unsigned short* bq0 = X0 + (size_t)(dy * 50 + dx) * 16;
            #pragma unroll
            for (int p = 0; p < 2; ++p) {
                wn[p * 2]     = *(const s8*)(wp + p * 1024);
                wn[p * 2 + 1] = *(const s8*)(wp + p * 1024 + 512);
                #pragma unroll
                for (int col = 0; col < 3; ++col) {
                    const unsigned short* bq = bq0 + (size_t)p * 160000 + col * 256;
                    xn[p * 6 + col * 2]     = *(const s8*)(bq);
                    xn[p * 6 + col * 2 + 1] = *(const s8*)(bq + 8);
                }
            }
        }
        #pragma unroll
        for (int p = 0; p < 2; ++p) {
            a0  = mm32(w[p * 2],     xr[p * 6 + 0], a0);   // hi*hi
            a0  = mm32(w[p * 2 + 1], xr[p * 6 + 0], a0);   // lo*hi
            a0  = mm32(w[p * 2],     xr[p * 6 + 1], a0);   // hi*lo
            a1  = mm32(w[p * 2],     xr[p * 6 + 2], a1);
            a1  = mm32(w[p * 2 + 1], xr[p * 6 + 2], a1);
            a1  = mm32(w[p * 2],     xr[p * 6 + 3], a1);
            a2c = mm32(w[p * 2],     xr[p * 6 + 4], a2c);
            a2c = mm32(w[p * 2 + 1], xr[p * 6 + 4], a2c);
            a2c = mm32(w[p * 2],     xr[p * 6 + 5], a2c);
        }
        if (tap < 8) __builtin_amdgcn_sched_group_barrier(0x020, 16, 0);
        __builtin_amdgcn_sched_group_barrier(0x008, 18, 0);
        if (tap < 8) {
            #pragma unroll
            for (int i = 0; i < 4; ++i)  w[i]  = wn[i];
            #pragma unroll
            for (int i = 0; i < 12; ++i) xr[i] = xn[i];
        }
    }

    f4 accs[3] = {a0, a1, a2c};
    int nh = n * 4 + wv;
    if (cv == 0) {
        // acc[r] = C[oc=quad*4+r][px=m16]; Qb tile [q][c] at m16*16+quad*4+r.
        unsigned short* dst = Qb + ((size_t)(nh * QTL + y * 3)) * 512 + m16 * 16 + quad * 4;
        #pragma unroll
        for (int xt = 0; xt < 3; ++xt) {
            s4 hi, lo;
            split4(accs[xt], hi, lo);
            *(s4*)(dst + xt * 512) = hi;
            *(s4*)(dst + xt * 512 + 256) = lo;
        }
    } else if (cv == 3) {
        // v2 row-sums -> a2m (sums; k_gates divides by 2116)
        #pragma unroll
        for (int r = 0; r < 4; ++r) {
            float t = a0[r] + a1[r] + ((m16 < 14) ? a2c[r] : 0.f);
            t += __shfl_xor(t, 1); t += __shfl_xor(t, 2);
            t += __shfl_xor(t, 4); t += __shfl_xor(t, 8);
            if (m16 == 0)
                atomicAdd(&a2m[n * CIN + wv * 16 + quad * 4 + r], t);
        }
    } else if (cv == 1) {
        // direct K tiles: slot (dloc*4 + cquad)*8 = [khi(c=4cq..+3) | klo(...)]
        unsigned short* dst = Kb + ((size_t)nh * NT + y * 3) * 512 + (m16 * 4 + quad) * 8;
        s8 z = (s8){0, 0, 0, 0, 0, 0, 0, 0};
        #pragma unroll
        for (int xt = 0; xt < 3; ++xt) {
            s4 hi, lo;
            split4(accs[xt], hi, lo);
            s8 st = __builtin_shufflevector(hi, lo, 0, 1, 2, 3, 4, 5, 6, 7);
            if (xt == 2 && m16 >= 14) st = z;       // x = 46,47 pads
            *(s8*)(dst + xt * 512) = st;
        }
    } else {
        // direct V dup-tiles via LDS transpose (per-wave-private region)
        #pragma unroll
        for (int xt = 0; xt < 3; ++xt)
            #pragma unroll
            for (int r = 0; r < 4; ++r)
                sv[wv][quad * 4 + r][xt * 16 + m16] = accs[xt][r];
        __syncthreads();
        int c = lane >> 2, dq = lane & 3;
        unsigned short* vb = Vb + ((size_t)nh * NT + y * 3) * 1024 + lane * 8;
        #pragma unroll
        for (int xt = 0; xt < 3; ++xt) {
            f4 v;
            #pragma unroll
            for (int j = 0; j < 4; ++j) {
                int xx = xt * 16 + dq * 4 + j;
                v[j] = (xx < 46) ? sv[wv][c][xx] : 0.f;
            }
            s4 hi, lo;
            split4(v, hi, lo);
            s8 h2 = __builtin_shufflevector(hi, hi, 0, 1, 2, 3, 0, 1, 2, 3);
            s8 l2 = __builtin_shufflevector(lo, lo, 0, 1, 2, 3, 0, 1, 2, 3);
            *(s8*)(vb + xt * 1024)       = h2;
            *(s8*)(vb + xt * 1024 + 512) = l2;
        }
    }
}

// ---------------------------------------------------------------------------
// MFMA attention, K=32 fused: QK = 2 mfma (was 3, + free lo*lo accuracy),
// PV = 2 mfma with A=[ph|pl] (natural concat) and B = dup-V from memory.
// NT=144, 18 iters per ds chunk. grid (72, 16), block 256.
__global__ __launch_bounds__(256) void k_mattn(const unsigned short* __restrict__ Qb,
                                               const unsigned short* __restrict__ Kb,
                                               const unsigned short* __restrict__ Vb,
                                               float* __restrict__ part) {
    __shared__ float sO[4][4][256];
    __shared__ float sl[4][4][64];
    int strip = blockIdx.x >> 1, hb = blockIdx.x & 1, nh = blockIdx.y;
    int lane = threadIdx.x & 63, wv = threadIdx.x >> 6;
    int ds = hb * 4 + wv;
    int q16 = lane & 15, quad = lane >> 4;

    s8 qhh[4], qll[4];          // [qh|qh], [ql|ql] dup built once in-register
    #pragma unroll
    for (int j = 0; j < 4; ++j) {
        const unsigned short* Qp = Qb + (size_t)(nh * QTL + strip * 4 + j) * 512
                                     + q16 * 16 + quad * 4;
        s4 qh = *(const s4*)(Qp);
        s4 ql = *(const s4*)(Qp + 256);
        qhh[j] = __builtin_shufflevector(qh, qh, 0, 1, 2, 3, 0, 1, 2, 3);
        qll[j] = __builtin_shufflevector(ql, ql, 0, 1, 2, 3, 0, 1, 2, 3);
    }
    f4 O[4];
    float l[4];
    #pragma unroll
    for (int j = 0; j < 4; ++j) { O[j] = (f4){0.f, 0.f, 0.f, 0.f}; l[j] = 0.f; }

    const unsigned short* Kp = Kb + (size_t)(nh * NT + ds * 18) * 512  + (q16 * 4 + quad) * 8;
    const unsigned short* Vp = Vb + (size_t)(nh * NT + ds * 18) * 1024 + (q16 * 4 + quad) * 8;
    s8 kk = *(const s8*)(Kp);
    s8 vh = *(const s8*)(Vp);
    s8 vl = *(const s8*)(Vp + 512);

    for (int it = 0; it < 18; ++it) {
        int nk = (it < 17) ? (it + 1) * 512 : 0;
        int nv = (it < 17) ? (it + 1) * 1024 : 0;
        s8 nkk = *(const s8*)(Kp + nk);
        s8 nvh = *(const s8*)(Vp + nv);
        s8 nvl = *(const s8*)(Vp + nv + 512);

        #pragma unroll
        for (int j = 0; j < 4; ++j) {
            f4 c1 = (f4){0.f, 0.f, 0.f, 0.f};
            c1 = mm32(kk, qhh[j], c1);      // khi*qh + klo*qh
            c1 = mm32(kk, qll[j], c1);      // khi*ql + klo*ql
            float p0 = __expf(c1.x), p1 = __expf(c1.y);
            float p2 = __expf(c1.z), p3 = __expf(c1.w);
            l[j] += (p0 + p1) + (p2 + p3);
            unsigned u0 = __builtin_bit_cast(unsigned, p0);
            unsigned u1 = __builtin_bit_cast(unsigned, p1);
            unsigned u2 = __builtin_bit_cast(unsigned, p2);
            unsigned u3 = __builtin_bit_cast(unsigned, p3);
            float r0 = p0 - __builtin_bit_cast(float, u0 & 0xffff0000u);
            float r1 = p1 - __builtin_bit_cast(float, u1 & 0xffff0000u);
            float r2 = p2 - __builtin_bit_cast(float, u2 & 0xffff0000u);
            float r3 = p3 - __builtin_bit_cast(float, u3 & 0xffff0000u);
            s8 pp;                           // [ph(4) | pl(4)]
            pp[0] = (short)(u0 >> 16); pp[1] = (short)(u1 >> 16);
            pp[2] = (short)(u2 >> 16); pp[3] = (short)(u3 >> 16);
            pp[4] = (short)(__builtin_bit_cast(unsigned, r0) >> 16);
            pp[5] = (short)(__builtin_bit_cast(unsigned, r1) >> 16);
            pp[6] = (short)(__builtin_bit_cast(unsigned, r2) >> 16);
            pp[7] = (short)(__builtin_bit_cast(unsigned, r3) >> 16);
            O[j] = mm32(pp, vh, O[j]);      // ph*vhi + pl*vhi
            O[j] = mm32(pp, vl, O[j]);      // ph*vlo + pl*vlo
        }
        kk = nkk; vh = nvh; vl = nvl;
    }

    // PV output is D[q][c]: lane(q16',quad') reg r -> q = quad'*4+r, c = q16'.
    // part wants index c*16 + q  ->  q16*16 + quad*4 + r.
    #pragma unroll
    for (int j = 0; j < 4; ++j) {
        sO[wv][j][q16 * 16 + quad * 4 + 0] = O[j].x;
        sO[wv][j][q16 * 16 + quad * 4 + 1] = O[j].y;
        sO[wv][j][q16 * 16 + quad * 4 + 2] = O[j].z;
        sO[wv][j][q16 * 16 + quad * 4 + 3] = O[j].w;
        sl[wv][j][quad * 16 + q16] = l[j];
    }
    __syncthreads();
    int t = threadIdx.x;
    float* pb = part + (size_t)((nh * 36 + strip) * 2 + hb) * 1280;
    #pragma unroll
    for (int j = 0; j < 4; ++j)
        pb[j * 256 + t] = (sO[0][j][t] + sO[1][j][t]) + (sO[2][j][t] + sO[3][j][t]);
    {
        int j2 = t >> 6, i2 = t & 63;
        pb[1024 + t] = (sl[0][j2][i2] + sl[1][j2][i2]) + (sl[2][j2][i2] + sl[3][j2][i2]);
    }
}

// ---------------------------------------------------------------------------
// Gates + LSTM + output 1x1 conv, fused with attention combine (-188 for the
// 188 zero-pad columns, each contributing exp(0)=1) and constant-gate
// projection (a2m holds SUMS; scale by 1/2116 here).
__global__ __launch_bounds__(256) void k_gates(const float* __restrict__ part,
                                               const float* __restrict__ a2m,
                                               const float* __restrict__ Wproj,
                                               const float* __restrict__ bg,
                                               const float* __restrict__ Wout,
                                               const float* __restrict__ bout,
                                               float* __restrict__ out) {
    __shared__ float a0s[64][16];
    __shared__ float wps[3][64][64];   // [gi][c][o]
    __shared__ float hs[16][68];
    __shared__ float invs[4][16];      // [h][px] softmax denominators
    __shared__ float c2s[3][64];       // constant gate pre-activations
    int n = blockIdx.y;
    int pt = blockIdx.x;
    int strip = pt >> 2, jq = pt & 3;
    int p0 = pt * 16;
    int tid = threadIdx.x;

    if (tid < 64) {                    // denominators
        int h = tid >> 4, q = tid & 15;
        const float* b0 = part + (size_t)(((n * 4 + h) * 36 + strip) * 2) * 1280;
        const float* b1 = b0 + 1280;
        float s = 0.f;
        #pragma unroll
        for (int quad = 0; quad < 4; ++quad)
            s += b0[1024 + jq * 64 + quad * 16 + q] + b1[1024 + jq * 64 + quad * 16 + q];
        invs[h][q] = 1.f / (s - 188.f);
    } else {                           // constant gates
        int gi = (tid - 64) >> 6, o = tid & 63;
        int g = (gi == 0) ? 0 : (gi == 1) ? 2 : 3;
        float acc = bg[g * CIN + o];
        const float* wp = Wproj + ((size_t)(g * 4 + 2) * CIN + o) * CIN;
        const float* am = a2m + n * CIN;
        #pragma unroll 8
        for (int c = 0; c < CIN; ++c) acc += wp[c] * (am[c] * (1.f / 2116.f));
        c2s[gi][o] = acc;
    }
    __syncthreads();

    for (int idx = tid; idx < 1024; idx += 256) {   // a0 tile from part
        int c = idx >> 4, px = idx & 15;
        int h = c >> 4, c16 = c & 15;
        const float* b0 = part + (size_t)(((n * 4 + h) * 36 + strip) * 2) * 1280;
        const float* b1 = b0 + 1280;
        int off = jq * 256 + c16 * 16 + px;
        a0s[c][px] = (b0[off] + b1[off]) * invs[h][px];
    }
    for (int idx = tid; idx < 12288; idx += 256) {
        int o = idx & 63; int rest = idx >> 6; int c = rest & 63; int gi = rest >> 6;
        int g = (gi == 0) ? 0 : (gi == 1) ? 2 : 3;
        wps[gi][c][o] = Wproj[((size_t)(g * 4 + 0) * CIN + o) * CIN + c];
    }
    __syncthreads();

    int o = tid & 63, pg = tid >> 6;
    float pi[4], pgt[4], po[4];
    {
        float ci = c2s[0][o], cg = c2s[1][o], co = c2s[2][o];
        #pragma unroll
        for (int j = 0; j < 4; ++j) { pi[j] = ci; pgt[j] = cg; po[j] = co; }
    }
    const float4* a4 = (const float4*)&a0s[0][0];
    #pragma unroll 4
    for (int c = 0; c < 64; ++c) {
        float4 av = a4[c * 4 + pg];
        float w0 = wps[0][c][o], w1 = wps[1][c][o], w2 = wps[2][c][o];
        pi[0]  += w0 * av.x; pi[1]  += w0 * av.y; pi[2]  += w0 * av.z; pi[3]  += w0 * av.w;
        pgt[0] += w1 * av.x; pgt[1] += w1 * av.y; pgt[2] += w1 * av.z; pgt[3] += w1 * av.w;
        po[0]  += w2 * av.x; po[1]  += w2 * av.y; po[2]  += w2 * av.z; po[3]  += w2 * av.w;
    }
    #pragma unroll
    for (int j = 0; j < 4; ++j) {
        float ii = 1.f / (1.f + __expf(-pi[j]));
        float gg = tanhf(pgt[j]);
        float oo = 1.f / (1.f + __expf(-po[j]));
        float cc = ii * gg;
        hs[pg * 4 + j][o] = oo * tanhf(cc);
    }
    __syncthreads();
    float acc[4];
    float bo = bout[o];
    #pragma unroll
    for (int j = 0; j < 4; ++j) acc[j] = bo;
    const float* wo = Wout + o * CIN;
    #pragma unroll 2
    for (int cg_ = 0; cg_ < 16; ++cg_) {
        float w0 = wo[cg_ * 4 + 0], w1 = wo[cg_ * 4 + 1], w2 = wo[cg_ * 4 + 2], w3 = wo[cg_ * 4 + 3];
        #pragma unroll
        for (int j = 0; j < 4; ++j) {
            const float4 hv = *(const float4*)&hs[pg * 4 + j][cg_ * 4];
            acc[j] += w0 * hv.x + w1 * hv.y + w2 * hv.z + w3 * hv.w;
        }
    }
    #pragma unroll
    for (int j = 0; j < 4; ++j)
        out[(size_t)(n * CIN + o) * HW + p0 + pg * 4 + j] = acc[j];
}

// ---------------------------------------------------------------------------
extern "C" void kernel_launch(void* const* d_in, const int* in_sizes, int n_in,
                              void* d_out, int out_size, void* d_ws, size_t ws_size,
                              hipStream_t stream) {
    const float* x     = (const float*)d_in[0];
    const float* W_in  = (const float*)d_in[1];
    const float* b_in  = (const float*)d_in[2];
    const float* Wq    = (const float*)d_in[3];
    const float* Wk    = (const float*)d_in[4];
    const float* Wv    = (const float*)d_in[5];
    const float* Wproj = (const float*)d_in[6];
    const float* b_g   = (const float*)d_in[7];
    const float* W_out = (const float*)d_in[8];
    const float* b_out = (const float*)d_in[9];
    float* out = (float*)d_out;

    float* a2m  = (float*)d_ws;                              // 256
    float* part = a2m + 256;                                 // 16*36*2*1280 = 1474560
    unsigned short* Qb = (unsigned short*)(part + 1474560);  // 16*144*512  = 1179648
    unsigned short* Kb = Qb + (size_t)16 * QTL * 512;        // 16*144*512  = 1179648
    unsigned short* Vb = Kb + (size_t)16 * NT * 512;         // 16*144*1024 = 2359296
    unsigned short* xb = Vb + (size_t)16 * NT * 1024;        // 32*2500*16  = 1280000
    unsigned short* Wb = xb + (size_t)32 * 2500 * 16;        // 16*9*2048   = 294912
    // total ~18.5 MB of workspace (was ~23 MB)

    k_xw    <<<dim3(801), 256, 0, stream>>>(x, W_in, b_in, Wq, Wk, Wv, xb, Wb, a2m, Kb, Vb);
    k_conv  <<<dim3(48, 4, 4), 256, 0, stream>>>(xb, Wb, Qb, Kb, Vb, a2m);
    k_mattn <<<dim3(72, 16), 256, 0, stream>>>(Qb, Kb, Vb, part);
    k_gates <<<dim3(144, 4), 256, 0, stream>>>(part, a2m, Wproj, b_g, W_out, b_out, out);
}